// Round 7
// baseline (655.162 us; speedup 1.0000x reference)
//
#include <hip/hip_runtime.h>
#include <hip/hip_bf16.h>

#define N_NODES 100000
#define N_EDGES 1600000
#define DIM 128
#define SCAN_CHUNK 1024

typedef __attribute__((ext_vector_type(8))) short bf16x8;
typedef __attribute__((ext_vector_type(4))) float f32x4;
typedef __attribute__((ext_vector_type(4))) short bf16x4;

// fp32 -> bf16 elementwise (RNE), 4 elems/thread
__global__ void cvt_kernel(const float* __restrict__ in, __hip_bfloat16* __restrict__ out, int n4) {
    int i = blockIdx.x * blockDim.x + threadIdx.x;
    if (i < n4) {
        f32x4 v = ((const f32x4*)in)[i];
        bf16x4 o;
        o.x = (short)__bfloat16_as_ushort(__float2bfloat16(v.x));
        o.y = (short)__bfloat16_as_ushort(__float2bfloat16(v.y));
        o.z = (short)__bfloat16_as_ushort(__float2bfloat16(v.z));
        o.w = (short)__bfloat16_as_ushort(__float2bfloat16(v.w));
        ((bf16x4*)out)[i] = o;
    }
}

// both 128x128 weights in one launch
__global__ void cvtw_kernel(const float* __restrict__ w1, const float* __restrict__ w2,
                            __hip_bfloat16* __restrict__ w1b, __hip_bfloat16* __restrict__ w2b) {
    int i = blockIdx.x * blockDim.x + threadIdx.x;
    if (i < DIM * DIM) {
        w1b[i] = __float2bfloat16(w1[i]);
        w2b[i] = __float2bfloat16(w2[i]);
    }
}

// degree count + per-edge within-dst rank (atomic return value, stored coalesced).
// Throughput-capped by device RMW-atomic rate (~23 G/s measured R5/R6); keep simple.
__global__ void degrank_kernel(const int* __restrict__ dst, int* __restrict__ deg,
                               int* __restrict__ rank) {
    for (int e = blockIdx.x * blockDim.x + threadIdx.x; e < N_EDGES; e += gridDim.x * blockDim.x)
        rank[e] = atomicAdd(&deg[dst[e]], 1);
}

// per-block partial sums over chunks of 1024
__global__ void scan1_kernel(const int* __restrict__ deg, int* __restrict__ bsum) {
    __shared__ int s[256];
    int t = threadIdx.x;
    int base = blockIdx.x * SCAN_CHUNK + t * 4;
    int v = 0;
    for (int k = 0; k < 4; k++) { int i = base + k; if (i < N_NODES) v += deg[i]; }
    s[t] = v;
    __syncthreads();
    for (int off = 128; off > 0; off >>= 1) { if (t < off) s[t] += s[t + off]; __syncthreads(); }
    if (t == 0) bsum[blockIdx.x] = s[0];
}

__global__ void scan2_kernel(const int* __restrict__ bsum, int* __restrict__ bscan,
                             int* __restrict__ row_start, int nb) {
    if (threadIdx.x == 0) {
        int run = 0;
        for (int b = 0; b < nb; b++) { bscan[b] = run; run += bsum[b]; }
        row_start[N_NODES] = run;
    }
}

__global__ void scan3_kernel(const int* __restrict__ deg, const int* __restrict__ bscan,
                             int* __restrict__ row_start) {
    __shared__ int s[256];
    int t = threadIdx.x;
    int base = blockIdx.x * SCAN_CHUNK + t * 4;
    int v[4]; int tot = 0;
    for (int k = 0; k < 4; k++) { int i = base + k; v[k] = (i < N_NODES) ? deg[i] : 0; tot += v[k]; }
    s[t] = tot;
    __syncthreads();
    for (int off = 1; off < 256; off <<= 1) {
        int a = (t >= off) ? s[t - off] : 0;
        __syncthreads();
        s[t] += a;
        __syncthreads();
    }
    int run = s[t] - tot + bscan[blockIdx.x];  // exclusive prefix for this thread
    for (int k = 0; k < 4; k++) {
        int i = base + k;
        if (i < N_NODES) row_start[i] = run;
        run += v[k];
    }
}

// atomic-free scatter, 4 edges per thread batched for ILP
#define FI_UNROLL 4
__global__ void fill_kernel(const int* __restrict__ src, const int* __restrict__ dst,
                            const float* __restrict__ ew, const int* __restrict__ rank,
                            const int* __restrict__ row_start, int2* __restrict__ sw_s) {
    int tid = blockIdx.x * blockDim.x + threadIdx.x;
    int nthreads = gridDim.x * blockDim.x;
    int d_[FI_UNROLL], r_[FI_UNROLL], s_[FI_UNROLL], w_[FI_UNROLL], rs_[FI_UNROLL];
#pragma unroll
    for (int k = 0; k < FI_UNROLL; k++) {
        int e = tid + k * nthreads;
        if (e < N_EDGES) {
            d_[k] = dst[e]; r_[k] = rank[e]; s_[k] = src[e]; w_[k] = __float_as_int(ew[e]);
        } else d_[k] = -1;
    }
#pragma unroll
    for (int k = 0; k < FI_UNROLL; k++)
        if (d_[k] >= 0) rs_[k] = row_start[d_[k]];
#pragma unroll
    for (int k = 0; k < FI_UNROLL; k++)
        if (d_[k] >= 0) sw_s[rs_[k] + r_[k]] = make_int2(s_[k], w_[k]);
}

// Fused aggregate + GEMM per layer. Block = 4 waves, 64 output rows.
// Each wave: aggregate its 16 nodes (lane = channel-pair, bf16x2 gathers),
// write rows to XOR-swizzled LDS tile, then MFMA 16x128 with A from LDS.
// No __syncthreads: each wave consumes only its own rows (wave-sync lgkmcnt).
template <int RELU, int ZERO0, int OUTBF>
__global__ __launch_bounds__(256) void aggmm_kernel(const __hip_bfloat16* __restrict__ x,
                                                    const int* __restrict__ row_start,
                                                    const int2* __restrict__ sw_s,
                                                    const float* __restrict__ eps, int li,
                                                    const __hip_bfloat16* __restrict__ W,
                                                    const float* __restrict__ bias,
                                                    void* __restrict__ outv) {
    __shared__ int2 s_sw[4][64];
    __shared__ __hip_bfloat162 s_h[4][16][64];  // 16 KB: per-wave 16 rows x 128 ch, swizzled
    int wv = threadIdx.x >> 6;
    int lane = threadIdx.x & 63;
    int row0 = blockIdx.x * 64 + wv * 16;
    const __hip_bfloat162* xp = (const __hip_bfloat162*)x;
    float ep = 1.0f + eps[li];

    // ---- aggregation phase: 16 nodes sequentially ----
    for (int j = 0; j < 16; j++) {
        int n = row0 + j;
        __hip_bfloat162 o;
        o.x = __float2bfloat16(0.f);
        o.y = __float2bfloat16(0.f);
        if (n < N_NODES) {
            int beg = row_start[n], end = row_start[n + 1];
            float ax = 0.f, ay = 0.f;
            for (int base = beg; base < end; base += 64) {
                int cnt = min(64, end - base);
                if (lane < cnt) s_sw[wv][lane] = sw_s[base + lane];
                asm volatile("s_waitcnt lgkmcnt(0)" ::: "memory");  // wave-sync staging
                int i = 0;
                for (; i + 4 <= cnt; i += 4) {
                    int2 e0 = s_sw[wv][i], e1 = s_sw[wv][i + 1];
                    int2 e2 = s_sw[wv][i + 2], e3 = s_sw[wv][i + 3];
                    __hip_bfloat162 v0 = xp[(size_t)e0.x * 64 + lane];
                    __hip_bfloat162 v1 = xp[(size_t)e1.x * 64 + lane];
                    __hip_bfloat162 v2 = xp[(size_t)e2.x * 64 + lane];
                    __hip_bfloat162 v3 = xp[(size_t)e3.x * 64 + lane];
                    float w0 = __int_as_float(e0.y), w1 = __int_as_float(e1.y);
                    float w2 = __int_as_float(e2.y), w3 = __int_as_float(e3.y);
                    ax += __bfloat162float(v0.x) * w0 + __bfloat162float(v1.x) * w1
                        + __bfloat162float(v2.x) * w2 + __bfloat162float(v3.x) * w3;
                    ay += __bfloat162float(v0.y) * w0 + __bfloat162float(v1.y) * w1
                        + __bfloat162float(v2.y) * w2 + __bfloat162float(v3.y) * w3;
                }
                for (; i < cnt; i++) {
                    int2 e = s_sw[wv][i];
                    __hip_bfloat162 v = xp[(size_t)e.x * 64 + lane];
                    float w = __int_as_float(e.y);
                    ax += __bfloat162float(v.x) * w;
                    ay += __bfloat162float(v.y) * w;
                }
                asm volatile("" ::: "memory");
            }
            int degn = end - beg;
            float dinv = degn > 0 ? 1.0f / (float)degn : 0.0f;
            __hip_bfloat162 xs = xp[(size_t)n * 64 + lane];
            o.x = __float2bfloat16(ep * __bfloat162float(xs.x) + ax * dinv);
            o.y = __float2bfloat16(ep * __bfloat162float(xs.y) + ay * dinv);
        }
        // swizzled LDS write: byte (lane*4) ^ ((j&7)<<4) within row j
        int co = (lane * 4) ^ ((j & 7) << 4);
        *(__hip_bfloat162*)((char*)&s_h[wv][j][0] + co) = o;
    }
    asm volatile("s_waitcnt lgkmcnt(0)" ::: "memory");  // all 16 rows visible to wave

    // ---- GEMM phase: A fragments from swizzled LDS ----
    int lr = lane & 15;   // A row within tile / row of W
    int kg = lane >> 4;   // k-subgroup (8 elements each)
    bf16x8 a[4];
#pragma unroll
    for (int k = 0; k < 4; k++) {
        int cb = (kg * 16 + k * 64) ^ ((lr & 7) << 4);
        a[k] = *(const bf16x8*)((const char*)&s_h[wv][lr][0] + cb);
    }

    f32x4 acc[8];
#pragma unroll
    for (int jt = 0; jt < 8; jt++) {
        const short* Wp = (const short*)W + (size_t)(jt * 16 + lr) * DIM + kg * 8;
        f32x4 c = {0.f, 0.f, 0.f, 0.f};
#pragma unroll
        for (int k = 0; k < 4; k++) {
            bf16x8 b = *(const bf16x8*)(Wp + k * 32);
            c = __builtin_amdgcn_mfma_f32_16x16x32_bf16(a[k], b, c, 0, 0, 0);
        }
        acc[jt] = c;
    }

    int colb = lane & 15;
    int rb = (lane >> 4) * 4;
#pragma unroll
    for (int jt = 0; jt < 8; jt++) {
        int col = jt * 16 + colb;
        float bv = bias[col];
#pragma unroll
        for (int r = 0; r < 4; r++) {
            int grow = row0 + rb + r;
            if (grow < N_NODES) {
                float v = acc[jt][r] + bv;
                if (RELU) v = fmaxf(v, 0.f);
                if (ZERO0 && grow == 0) v = 0.f;
                if (OUTBF)
                    ((__hip_bfloat16*)outv)[(size_t)grow * DIM + col] = __float2bfloat16(v);
                else
                    ((float*)outv)[(size_t)grow * DIM + col] = v;
            }
        }
    }
}

extern "C" void kernel_launch(void* const* d_in, const int* in_sizes, int n_in,
                              void* d_out, int out_size, void* d_ws, size_t ws_size,
                              hipStream_t stream) {
    const float* emb = (const float*)d_in[0];
    const float* w1  = (const float*)d_in[1];
    const float* b1  = (const float*)d_in[2];
    const float* w2  = (const float*)d_in[3];
    const float* b2  = (const float*)d_in[4];
    const float* eps = (const float*)d_in[5];
    const float* ew  = (const float*)d_in[6];
    const int* src   = (const int*)d_in[7];
    const int* dst   = (const int*)d_in[8];
    float* out = (float*)d_out;

    char* base = (char*)d_ws;
    size_t off = 0;
    auto alloc = [&](size_t bytes) -> char* {
        char* p = base + off;
        off += (bytes + 255) & ~(size_t)255;
        return p;
    };
    int* deg            = (int*)alloc((size_t)N_NODES * 4);
    int* row_start      = (int*)alloc((size_t)(N_NODES + 1) * 4);
    int* rank           = (int*)alloc((size_t)N_EDGES * 4);
    int* bsum           = (int*)alloc(128 * 4);
    int* bscan          = (int*)alloc(128 * 4);
    int2* sw_s          = (int2*)alloc((size_t)N_EDGES * 8);
    __hip_bfloat16* xb  = (__hip_bfloat16*)alloc((size_t)N_NODES * DIM * 2);
    __hip_bfloat16* xc  = (__hip_bfloat16*)alloc((size_t)N_NODES * DIM * 2);
    __hip_bfloat16* embb= (__hip_bfloat16*)alloc((size_t)N_NODES * DIM * 2);
    __hip_bfloat16* w1b = (__hip_bfloat16*)alloc(DIM * DIM * 2);
    __hip_bfloat16* w2b = (__hip_bfloat16*)alloc(DIM * DIM * 2);

    hipMemsetAsync(deg, 0, (size_t)N_NODES * 4, stream);

    // dtype conversions
    cvt_kernel<<<(N_NODES * DIM / 4 + 255) / 256, 256, 0, stream>>>(emb, embb, N_NODES * DIM / 4);
    cvtw_kernel<<<(DIM * DIM + 255) / 256, 256, 0, stream>>>(w1, w2, w1b, w2b);

    // CSR build (atomic-free scatter via precomputed ranks)
    degrank_kernel<<<2048, 256, 0, stream>>>(dst, deg, rank);
    int nb = (N_NODES + SCAN_CHUNK - 1) / SCAN_CHUNK;
    scan1_kernel<<<nb, 256, 0, stream>>>(deg, bsum);
    scan2_kernel<<<1, 64, 0, stream>>>(bsum, bscan, row_start, nb);
    scan3_kernel<<<nb, 256, 0, stream>>>(deg, bscan, row_start);
    {
        int nthreads = ((N_EDGES + FI_UNROLL - 1) / FI_UNROLL + 255) & ~255;
        fill_kernel<<<nthreads / 256, 256, 0, stream>>>(src, dst, ew, rank, row_start, sw_s);
    }

    // fused layers (ping-pong buffers: embb -> xb -> xc -> out)
    int blocks = (N_NODES + 63) / 64;
    aggmm_kernel<1, 0, 1><<<blocks, 256, 0, stream>>>(embb, row_start, sw_s, eps, 0, w1b, b1, xb);
    aggmm_kernel<1, 0, 1><<<blocks, 256, 0, stream>>>(xb,   row_start, sw_s, eps, 1, w2b, b2, xc);
    aggmm_kernel<0, 1, 0><<<blocks, 256, 0, stream>>>(xc,   row_start, sw_s, eps, 2, w2b, b2, out);
}

// Round 8
// 521.073 us; speedup vs baseline: 1.2573x; 1.2573x over previous
//
#include <hip/hip_runtime.h>
#include <hip/hip_bf16.h>

#define N_NODES 100000
#define N_EDGES 1600000
#define DIM 128
#define SCAN_CHUNK 1024

typedef __attribute__((ext_vector_type(8))) short bf16x8;
typedef __attribute__((ext_vector_type(4))) float f32x4;
typedef __attribute__((ext_vector_type(4))) short bf16x4;

// fp32 -> bf16 for emb + w1 + w2 in ONE launch (4 elems/thread)
__global__ void cvtall_kernel(const float* __restrict__ emb, const float* __restrict__ w1,
                              const float* __restrict__ w2, __hip_bfloat16* __restrict__ embb,
                              __hip_bfloat16* __restrict__ w1b, __hip_bfloat16* __restrict__ w2b) {
    const int n4e = N_NODES * DIM / 4;
    const int n4w = DIM * DIM / 4;
    int i = blockIdx.x * blockDim.x + threadIdx.x;
    const float* in;
    __hip_bfloat16* out;
    int j;
    if (i < n4e) { in = emb; out = embb; j = i; }
    else if (i < n4e + n4w) { in = w1; out = w1b; j = i - n4e; }
    else if (i < n4e + 2 * n4w) { in = w2; out = w2b; j = i - n4e - n4w; }
    else return;
    f32x4 v = ((const f32x4*)in)[j];
    bf16x4 o;
    o.x = (short)__bfloat16_as_ushort(__float2bfloat16(v.x));
    o.y = (short)__bfloat16_as_ushort(__float2bfloat16(v.y));
    o.z = (short)__bfloat16_as_ushort(__float2bfloat16(v.z));
    o.w = (short)__bfloat16_as_ushort(__float2bfloat16(v.w));
    ((bf16x4*)out)[j] = o;
}

// degree count + per-edge within-dst rank (atomic return value, stored coalesced).
// Device returning-RMW throughput cap ~23 G/s (R5/R6 measured); simple form is fastest.
__global__ void degrank_kernel(const int* __restrict__ dst, int* __restrict__ deg,
                               int* __restrict__ rank) {
    for (int e = blockIdx.x * blockDim.x + threadIdx.x; e < N_EDGES; e += gridDim.x * blockDim.x)
        rank[e] = atomicAdd(&deg[dst[e]], 1);
}

// per-block partial sums over chunks of 1024
__global__ void scan1_kernel(const int* __restrict__ deg, int* __restrict__ bsum) {
    __shared__ int s[256];
    int t = threadIdx.x;
    int base = blockIdx.x * SCAN_CHUNK + t * 4;
    int v = 0;
    for (int k = 0; k < 4; k++) { int i = base + k; if (i < N_NODES) v += deg[i]; }
    s[t] = v;
    __syncthreads();
    for (int off = 128; off > 0; off >>= 1) { if (t < off) s[t] += s[t + off]; __syncthreads(); }
    if (t == 0) bsum[blockIdx.x] = s[0];
}

__global__ void scan2_kernel(const int* __restrict__ bsum, int* __restrict__ bscan,
                             int* __restrict__ row_start, int nb) {
    if (threadIdx.x == 0) {
        int run = 0;
        for (int b = 0; b < nb; b++) { bscan[b] = run; run += bsum[b]; }
        row_start[N_NODES] = run;
    }
}

__global__ void scan3_kernel(const int* __restrict__ deg, const int* __restrict__ bscan,
                             int* __restrict__ row_start) {
    __shared__ int s[256];
    int t = threadIdx.x;
    int base = blockIdx.x * SCAN_CHUNK + t * 4;
    int v[4]; int tot = 0;
    for (int k = 0; k < 4; k++) { int i = base + k; v[k] = (i < N_NODES) ? deg[i] : 0; tot += v[k]; }
    s[t] = tot;
    __syncthreads();
    for (int off = 1; off < 256; off <<= 1) {
        int a = (t >= off) ? s[t - off] : 0;
        __syncthreads();
        s[t] += a;
        __syncthreads();
    }
    int run = s[t] - tot + bscan[blockIdx.x];  // exclusive prefix for this thread
    for (int k = 0; k < 4; k++) {
        int i = base + k;
        if (i < N_NODES) row_start[i] = run;
        run += v[k];
    }
}

// atomic-free scatter, 4 edges per thread batched for ILP
#define FI_UNROLL 4
__global__ void fill_kernel(const int* __restrict__ src, const int* __restrict__ dst,
                            const float* __restrict__ ew, const int* __restrict__ rank,
                            const int* __restrict__ row_start, int2* __restrict__ sw_s) {
    int tid = blockIdx.x * blockDim.x + threadIdx.x;
    int nthreads = gridDim.x * blockDim.x;
    int d_[FI_UNROLL], r_[FI_UNROLL], s_[FI_UNROLL], w_[FI_UNROLL], rs_[FI_UNROLL];
#pragma unroll
    for (int k = 0; k < FI_UNROLL; k++) {
        int e = tid + k * nthreads;
        if (e < N_EDGES) {
            d_[k] = dst[e]; r_[k] = rank[e]; s_[k] = src[e]; w_[k] = __float_as_int(ew[e]);
        } else d_[k] = -1;
    }
#pragma unroll
    for (int k = 0; k < FI_UNROLL; k++)
        if (d_[k] >= 0) rs_[k] = row_start[d_[k]];
#pragma unroll
    for (int k = 0; k < FI_UNROLL; k++)
        if (d_[k] >= 0) sw_s[rs_[k] + r_[k]] = make_int2(s_[k], w_[k]);
}

// Fused aggregate + GEMM. Block = 4 waves owns a 16-ROW tile.
// Agg: each wave aggregates 4 nodes (lane = channel-pair, bf16x2 gathers, round-5 inner
// loop), writes rows to a shared XOR-swizzled 16x128 LDS tile. __syncthreads.
// GEMM: column-split across waves — each wave computes 16 rows x 32 cols (2 jt x 4 MFMA).
template <int RELU, int ZERO0, int OUTBF>
__global__ __launch_bounds__(256) void aggmm_kernel(const __hip_bfloat16* __restrict__ x,
                                                    const int* __restrict__ row_start,
                                                    const int2* __restrict__ sw_s,
                                                    const float* __restrict__ eps, int li,
                                                    const __hip_bfloat16* __restrict__ W,
                                                    const float* __restrict__ bias,
                                                    void* __restrict__ outv) {
    __shared__ int2 s_sw[4][64];
    __shared__ __hip_bfloat162 s_h[16][64];  // 4 KB: 16 rows x 128 ch, XOR-swizzled
    int wv = threadIdx.x >> 6;
    int lane = threadIdx.x & 63;
    int row0 = blockIdx.x * 16;
    const __hip_bfloat162* xp = (const __hip_bfloat162*)x;
    float ep = 1.0f + eps[li];

    // ---- aggregation phase: 4 nodes per wave ----
    for (int jj = 0; jj < 4; jj++) {
        int j = wv * 4 + jj;  // row in tile
        int n = row0 + j;
        __hip_bfloat162 o;
        o.x = __float2bfloat16(0.f);
        o.y = __float2bfloat16(0.f);
        if (n < N_NODES) {
            int beg = row_start[n], end = row_start[n + 1];
            float ax = 0.f, ay = 0.f;
            for (int base = beg; base < end; base += 64) {
                int cnt = min(64, end - base);
                if (lane < cnt) s_sw[wv][lane] = sw_s[base + lane];
                asm volatile("s_waitcnt lgkmcnt(0)" ::: "memory");  // wave-sync staging
                int i = 0;
                for (; i + 4 <= cnt; i += 4) {
                    int2 e0 = s_sw[wv][i], e1 = s_sw[wv][i + 1];
                    int2 e2 = s_sw[wv][i + 2], e3 = s_sw[wv][i + 3];
                    __hip_bfloat162 v0 = xp[(size_t)e0.x * 64 + lane];
                    __hip_bfloat162 v1 = xp[(size_t)e1.x * 64 + lane];
                    __hip_bfloat162 v2 = xp[(size_t)e2.x * 64 + lane];
                    __hip_bfloat162 v3 = xp[(size_t)e3.x * 64 + lane];
                    float w0 = __int_as_float(e0.y), w1 = __int_as_float(e1.y);
                    float w2 = __int_as_float(e2.y), w3 = __int_as_float(e3.y);
                    ax += __bfloat162float(v0.x) * w0 + __bfloat162float(v1.x) * w1
                        + __bfloat162float(v2.x) * w2 + __bfloat162float(v3.x) * w3;
                    ay += __bfloat162float(v0.y) * w0 + __bfloat162float(v1.y) * w1
                        + __bfloat162float(v2.y) * w2 + __bfloat162float(v3.y) * w3;
                }
                for (; i < cnt; i++) {
                    int2 e = s_sw[wv][i];
                    __hip_bfloat162 v = xp[(size_t)e.x * 64 + lane];
                    float w = __int_as_float(e.y);
                    ax += __bfloat162float(v.x) * w;
                    ay += __bfloat162float(v.y) * w;
                }
                asm volatile("" ::: "memory");
            }
            int degn = end - beg;
            float dinv = degn > 0 ? 1.0f / (float)degn : 0.0f;
            __hip_bfloat162 xs = xp[(size_t)n * 64 + lane];
            o.x = __float2bfloat16(ep * __bfloat162float(xs.x) + ax * dinv);
            o.y = __float2bfloat16(ep * __bfloat162float(xs.y) + ay * dinv);
        }
        // swizzled LDS write: byte (lane*4) ^ ((row&7)<<4)
        int co = (lane * 4) ^ ((j & 7) << 4);
        *(__hip_bfloat162*)((char*)&s_h[j][0] + co) = o;
    }
    __syncthreads();  // tile produced by all 4 waves

    // ---- GEMM phase: each wave does cols [wv*32, wv*32+32) ----
    int lr = lane & 15;   // A/W row
    int kg = lane >> 4;   // k-subgroup (8 elements each)
    bf16x8 a[4];
#pragma unroll
    for (int k = 0; k < 4; k++) {
        int cb = (kg * 16 + k * 64) ^ ((lr & 7) << 4);
        a[k] = *(const bf16x8*)((const char*)&s_h[lr][0] + cb);
    }

    f32x4 acc[2];
#pragma unroll
    for (int t = 0; t < 2; t++) {
        int jt = wv * 2 + t;
        const short* Wp = (const short*)W + (size_t)(jt * 16 + lr) * DIM + kg * 8;
        f32x4 c = {0.f, 0.f, 0.f, 0.f};
#pragma unroll
        for (int k = 0; k < 4; k++) {
            bf16x8 b = *(const bf16x8*)(Wp + k * 32);
            c = __builtin_amdgcn_mfma_f32_16x16x32_bf16(a[k], b, c, 0, 0, 0);
        }
        acc[t] = c;
    }

    int colb = lane & 15;
    int rb = (lane >> 4) * 4;
#pragma unroll
    for (int t = 0; t < 2; t++) {
        int col = (wv * 2 + t) * 16 + colb;
        float bv = bias[col];
#pragma unroll
        for (int r = 0; r < 4; r++) {
            int grow = row0 + rb + r;
            if (grow < N_NODES) {
                float v = acc[t][r] + bv;
                if (RELU) v = fmaxf(v, 0.f);
                if (ZERO0 && grow == 0) v = 0.f;
                if (OUTBF)
                    ((__hip_bfloat16*)outv)[(size_t)grow * DIM + col] = __float2bfloat16(v);
                else
                    ((float*)outv)[(size_t)grow * DIM + col] = v;
            }
        }
    }
}

extern "C" void kernel_launch(void* const* d_in, const int* in_sizes, int n_in,
                              void* d_out, int out_size, void* d_ws, size_t ws_size,
                              hipStream_t stream) {
    const float* emb = (const float*)d_in[0];
    const float* w1  = (const float*)d_in[1];
    const float* b1  = (const float*)d_in[2];
    const float* w2  = (const float*)d_in[3];
    const float* b2  = (const float*)d_in[4];
    const float* eps = (const float*)d_in[5];
    const float* ew  = (const float*)d_in[6];
    const int* src   = (const int*)d_in[7];
    const int* dst   = (const int*)d_in[8];
    float* out = (float*)d_out;

    char* base = (char*)d_ws;
    size_t off = 0;
    auto alloc = [&](size_t bytes) -> char* {
        char* p = base + off;
        off += (bytes + 255) & ~(size_t)255;
        return p;
    };
    int* deg            = (int*)alloc((size_t)N_NODES * 4);
    int* row_start      = (int*)alloc((size_t)(N_NODES + 1) * 4);
    int* rank           = (int*)alloc((size_t)N_EDGES * 4);
    int* bsum           = (int*)alloc(128 * 4);
    int* bscan          = (int*)alloc(128 * 4);
    int2* sw_s          = (int2*)alloc((size_t)N_EDGES * 8);
    __hip_bfloat16* xb  = (__hip_bfloat16*)alloc((size_t)N_NODES * DIM * 2);
    __hip_bfloat16* xc  = (__hip_bfloat16*)alloc((size_t)N_NODES * DIM * 2);
    __hip_bfloat16* embb= (__hip_bfloat16*)alloc((size_t)N_NODES * DIM * 2);
    __hip_bfloat16* w1b = (__hip_bfloat16*)alloc(DIM * DIM * 2);
    __hip_bfloat16* w2b = (__hip_bfloat16*)alloc(DIM * DIM * 2);

    hipMemsetAsync(deg, 0, (size_t)N_NODES * 4, stream);

    // dtype conversions (one launch)
    {
        int n4 = N_NODES * DIM / 4 + 2 * (DIM * DIM / 4);
        cvtall_kernel<<<(n4 + 255) / 256, 256, 0, stream>>>(emb, w1, w2, embb, w1b, w2b);
    }

    // CSR build (atomic-free scatter via precomputed ranks)
    degrank_kernel<<<2048, 256, 0, stream>>>(dst, deg, rank);
    int nb = (N_NODES + SCAN_CHUNK - 1) / SCAN_CHUNK;
    scan1_kernel<<<nb, 256, 0, stream>>>(deg, bsum);
    scan2_kernel<<<1, 64, 0, stream>>>(bsum, bscan, row_start, nb);
    scan3_kernel<<<nb, 256, 0, stream>>>(deg, bscan, row_start);
    {
        int nthreads = ((N_EDGES + FI_UNROLL - 1) / FI_UNROLL + 255) & ~255;
        fill_kernel<<<nthreads / 256, 256, 0, stream>>>(src, dst, ew, rank, row_start, sw_s);
    }

    // fused layers (ping-pong buffers: embb -> xb -> xc -> out)
    int blocks = (N_NODES + 15) / 16;
    aggmm_kernel<1, 0, 1><<<blocks, 256, 0, stream>>>(embb, row_start, sw_s, eps, 0, w1b, b1, xb);
    aggmm_kernel<1, 0, 1><<<blocks, 256, 0, stream>>>(xb,   row_start, sw_s, eps, 1, w2b, b2, xc);
    aggmm_kernel<0, 1, 0><<<blocks, 256, 0, stream>>>(xc,   row_start, sw_s, eps, 2, w2b, b2, out);
}

// Round 10
// 498.013 us; speedup vs baseline: 1.3156x; 1.0463x over previous
//
#include <hip/hip_runtime.h>
#include <hip/hip_bf16.h>

#define N_NODES 100000
#define N_EDGES 1600000
#define DIM 128
#define SCAN_CHUNK 1024

typedef __attribute__((ext_vector_type(8))) short bf16x8;
typedef __attribute__((ext_vector_type(4))) float f32x4;
typedef __attribute__((ext_vector_type(4))) short bf16x4;

__device__ __forceinline__ float b2f(short s) {
    return __uint_as_float(((unsigned int)(unsigned short)s) << 16);
}

// fp32 -> bf16 for emb + w1 + w2 in ONE launch (4 elems/thread)
__global__ void cvtall_kernel(const float* __restrict__ emb, const float* __restrict__ w1,
                              const float* __restrict__ w2, __hip_bfloat16* __restrict__ embb,
                              __hip_bfloat16* __restrict__ w1b, __hip_bfloat16* __restrict__ w2b) {
    const int n4e = N_NODES * DIM / 4;
    const int n4w = DIM * DIM / 4;
    int i = blockIdx.x * blockDim.x + threadIdx.x;
    const float* in;
    __hip_bfloat16* out;
    int j;
    if (i < n4e) { in = emb; out = embb; j = i; }
    else if (i < n4e + n4w) { in = w1; out = w1b; j = i - n4e; }
    else if (i < n4e + 2 * n4w) { in = w2; out = w2b; j = i - n4e - n4w; }
    else return;
    f32x4 v = ((const f32x4*)in)[j];
    bf16x4 o;
    o.x = (short)__bfloat16_as_ushort(__float2bfloat16(v.x));
    o.y = (short)__bfloat16_as_ushort(__float2bfloat16(v.y));
    o.z = (short)__bfloat16_as_ushort(__float2bfloat16(v.z));
    o.w = (short)__bfloat16_as_ushort(__float2bfloat16(v.w));
    ((bf16x4*)out)[j] = o;
}

// degree count + per-edge within-dst rank at FULL residency (2048x256 threads).
// 4 slots/thread: slots 0-2 always in-bounds (3S < N_EDGES), slot 3 covers the tail.
// (R9 bug: 3 slots covered only 1,572,864 of 1,600,000 edges -> poison ranks -> OOB.)
__global__ __launch_bounds__(256) void degrank_kernel(const int* __restrict__ dst,
                                                      int* __restrict__ deg,
                                                      int* __restrict__ rank) {
    const int S = 2048 * 256;
    int tid = blockIdx.x * blockDim.x + threadIdx.x;
    int e3 = tid + 3 * S;
    int d0 = dst[tid];
    int d1 = dst[tid + S];
    int d2 = dst[tid + 2 * S];
    int d3 = (e3 < N_EDGES) ? dst[e3] : -1;
    int r0 = atomicAdd(&deg[d0], 1);
    int r1 = atomicAdd(&deg[d1], 1);
    int r2 = atomicAdd(&deg[d2], 1);
    int r3 = (d3 >= 0) ? atomicAdd(&deg[d3], 1) : 0;
    rank[tid] = r0;
    rank[tid + S] = r1;
    rank[tid + 2 * S] = r2;
    if (e3 < N_EDGES) rank[e3] = r3;
}

// per-block partial sums over chunks of 1024
__global__ void scan1_kernel(const int* __restrict__ deg, int* __restrict__ bsum) {
    __shared__ int s[256];
    int t = threadIdx.x;
    int base = blockIdx.x * SCAN_CHUNK + t * 4;
    int v = 0;
    for (int k = 0; k < 4; k++) { int i = base + k; if (i < N_NODES) v += deg[i]; }
    s[t] = v;
    __syncthreads();
    for (int off = 128; off > 0; off >>= 1) { if (t < off) s[t] += s[t + off]; __syncthreads(); }
    if (t == 0) bsum[blockIdx.x] = s[0];
}

__global__ void scan2_kernel(const int* __restrict__ bsum, int* __restrict__ bscan,
                             int* __restrict__ row_start, int nb) {
    if (threadIdx.x == 0) {
        int run = 0;
        for (int b = 0; b < nb; b++) { bscan[b] = run; run += bsum[b]; }
        row_start[N_NODES] = run;
    }
}

__global__ void scan3_kernel(const int* __restrict__ deg, const int* __restrict__ bscan,
                             int* __restrict__ row_start) {
    __shared__ int s[256];
    int t = threadIdx.x;
    int base = blockIdx.x * SCAN_CHUNK + t * 4;
    int v[4]; int tot = 0;
    for (int k = 0; k < 4; k++) { int i = base + k; v[k] = (i < N_NODES) ? deg[i] : 0; tot += v[k]; }
    s[t] = tot;
    __syncthreads();
    for (int off = 1; off < 256; off <<= 1) {
        int a = (t >= off) ? s[t - off] : 0;
        __syncthreads();
        s[t] += a;
        __syncthreads();
    }
    int run = s[t] - tot + bscan[blockIdx.x];  // exclusive prefix for this thread
    for (int k = 0; k < 4; k++) {
        int i = base + k;
        if (i < N_NODES) row_start[i] = run;
        run += v[k];
    }
}

// atomic-free scatter, 4 edges per thread batched for ILP.
// Stores PRE-SCALED src row byte-offset (src*256) to save per-edge addr math in agg.
#define FI_UNROLL 4
__global__ void fill_kernel(const int* __restrict__ src, const int* __restrict__ dst,
                            const float* __restrict__ ew, const int* __restrict__ rank,
                            const int* __restrict__ row_start, int2* __restrict__ sw_s) {
    int tid = blockIdx.x * blockDim.x + threadIdx.x;
    int nthreads = gridDim.x * blockDim.x;
    int d_[FI_UNROLL], r_[FI_UNROLL], s_[FI_UNROLL], w_[FI_UNROLL], rs_[FI_UNROLL];
#pragma unroll
    for (int k = 0; k < FI_UNROLL; k++) {
        int e = tid + k * nthreads;
        if (e < N_EDGES) {
            d_[k] = dst[e]; r_[k] = rank[e]; s_[k] = src[e] << 8; w_[k] = __float_as_int(ew[e]);
        } else d_[k] = -1;
    }
#pragma unroll
    for (int k = 0; k < FI_UNROLL; k++)
        if (d_[k] >= 0) rs_[k] = row_start[d_[k]];
#pragma unroll
    for (int k = 0; k < FI_UNROLL; k++)
        if (d_[k] >= 0) sw_s[rs_[k] + r_[k]] = make_int2(s_[k], w_[k]);
}

// Fused aggregate + GEMM. Block = 4 waves owns a 16-row tile (N_NODES % 16 == 0).
// Agg: half-wave edge pairing — lane owns 4 channels (bf16x4 8B gathers); lanes 0-31
// process even edges, 32-63 odd edges; __shfl_xor(·,32) combines per node.
// GEMM: column-split across waves (16 rows x 32 cols each).
// bf16 out goes through LDS for full-sector coalesced stores.
template <int RELU, int ZERO0, int OUTBF>
__global__ __launch_bounds__(256) void aggmm_kernel(const __hip_bfloat16* __restrict__ x,
                                                    const int* __restrict__ row_start,
                                                    const int2* __restrict__ sw_s,
                                                    const float* __restrict__ eps, int li,
                                                    const __hip_bfloat16* __restrict__ W,
                                                    const float* __restrict__ bias,
                                                    void* __restrict__ outv) {
    __shared__ int2 s_sw[4][66];
    __shared__ __hip_bfloat162 s_h[16][64];  // 4 KB tile, XOR-swizzled
    int wv = threadIdx.x >> 6;
    int lane = threadIdx.x & 63;
    int row0 = blockIdx.x * 16;
    int c = lane & 31;        // channel group: channels [4c, 4c+4)
    int half = lane >> 5;     // 0: even edges, 1: odd edges
    const char* xb = (const char*)x + (c << 3);
    float ep = 1.0f + eps[li];

    // ---- aggregation phase: 4 nodes per wave ----
    for (int jj = 0; jj < 4; jj++) {
        int j = wv * 4 + jj;  // row in tile
        int n = row0 + j;
        int beg = row_start[n], end = row_start[n + 1];
        float a0 = 0.f, a1 = 0.f, a2 = 0.f, a3 = 0.f;
        for (int base = beg; base < end; base += 64) {
            int cnt = min(64, end - base);
            if (lane < cnt) s_sw[wv][lane] = sw_s[base + lane];
            else if (lane == cnt) s_sw[wv][lane] = make_int2(0, 0);  // zero-weight pad
            asm volatile("s_waitcnt lgkmcnt(0)" ::: "memory");  // wave-sync staging
            int cnt2 = (cnt + 1) & ~1;
            int i = 0;
            for (; i + 4 <= cnt2; i += 4) {
                int2 ea = s_sw[wv][i + half];
                int2 eb = s_sw[wv][i + 2 + half];
                bf16x4 va = *(const bf16x4*)(xb + ea.x);
                bf16x4 vb = *(const bf16x4*)(xb + eb.x);
                float wa = __int_as_float(ea.y), wb = __int_as_float(eb.y);
                a0 += b2f(va.x) * wa + b2f(vb.x) * wb;
                a1 += b2f(va.y) * wa + b2f(vb.y) * wb;
                a2 += b2f(va.z) * wa + b2f(vb.z) * wb;
                a3 += b2f(va.w) * wa + b2f(vb.w) * wb;
            }
            for (; i < cnt2; i += 2) {
                int2 e = s_sw[wv][i + half];
                bf16x4 v = *(const bf16x4*)(xb + e.x);
                float w = __int_as_float(e.y);
                a0 += b2f(v.x) * w;
                a1 += b2f(v.y) * w;
                a2 += b2f(v.z) * w;
                a3 += b2f(v.w) * w;
            }
            asm volatile("" ::: "memory");
        }
        // combine even/odd halves
        a0 += __shfl_xor(a0, 32, 64);
        a1 += __shfl_xor(a1, 32, 64);
        a2 += __shfl_xor(a2, 32, 64);
        a3 += __shfl_xor(a3, 32, 64);
        if (half == 0) {
            int degn = end - beg;
            float dinv = degn > 0 ? 1.0f / (float)degn : 0.0f;
            bf16x4 xs = *(const bf16x4*)((const char*)x + (size_t)n * 256 + (c << 3));
            bf16x4 o;
            o.x = (short)__bfloat16_as_ushort(__float2bfloat16(ep * b2f(xs.x) + a0 * dinv));
            o.y = (short)__bfloat16_as_ushort(__float2bfloat16(ep * b2f(xs.y) + a1 * dinv));
            o.z = (short)__bfloat16_as_ushort(__float2bfloat16(ep * b2f(xs.z) + a2 * dinv));
            o.w = (short)__bfloat16_as_ushort(__float2bfloat16(ep * b2f(xs.w) + a3 * dinv));
            int co = (c * 8) ^ ((j & 7) << 4);
            *(bf16x4*)((char*)&s_h[j][0] + co) = o;
        }
    }
    __syncthreads();  // tile produced by all 4 waves

    // ---- GEMM phase: each wave does cols [wv*32, wv*32+32) ----
    int lr = lane & 15;   // A/W row
    int kg = lane >> 4;   // k-subgroup (8 elements each)
    bf16x8 a[4];
#pragma unroll
    for (int k = 0; k < 4; k++) {
        int cb = (kg * 16 + k * 64) ^ ((lr & 7) << 4);
        a[k] = *(const bf16x8*)((const char*)&s_h[lr][0] + cb);
    }
    __syncthreads();  // a-frags in registers; s_h free for epilogue reuse

    f32x4 acc[2];
#pragma unroll
    for (int t = 0; t < 2; t++) {
        int jt = wv * 2 + t;
        const short* Wp = (const short*)W + (size_t)(jt * 16 + lr) * DIM + kg * 8;
        f32x4 cc = {0.f, 0.f, 0.f, 0.f};
#pragma unroll
        for (int k = 0; k < 4; k++) {
            bf16x8 b = *(const bf16x8*)(Wp + k * 32);
            cc = __builtin_amdgcn_mfma_f32_16x16x32_bf16(a[k], b, cc, 0, 0, 0);
        }
        acc[t] = cc;
    }

    int colb = lane & 15;
    int rb = (lane >> 4) * 4;
    if (OUTBF) {
        // stage out-tile in LDS (row-XOR swizzle), then 256 x 16B coalesced stores
#pragma unroll
        for (int t = 0; t < 2; t++) {
            int col = (wv * 2 + t) * 16 + colb;
            float bv = bias[col];
#pragma unroll
            for (int r = 0; r < 4; r++) {
                int row = rb + r;
                float v = acc[t][r] + bv;
                if (RELU) v = fmaxf(v, 0.f);
                if (ZERO0 && blockIdx.x == 0 && row == 0) v = 0.f;
                int bo = (row * 256 + col * 2) ^ ((row & 7) << 4);
                *(__hip_bfloat16*)((char*)s_h + bo) = __float2bfloat16(v);
            }
        }
        __syncthreads();
        int row = threadIdx.x >> 4, c16 = threadIdx.x & 15;
        int bo = (row * 256 + c16 * 16) ^ ((row & 7) << 4);
        bf16x8 vv = *(const bf16x8*)((const char*)s_h + bo);
        *(bf16x8*)((char*)outv + (size_t)(row0 + row) * 256 + c16 * 16) = vv;
    } else {
#pragma unroll
        for (int t = 0; t < 2; t++) {
            int col = (wv * 2 + t) * 16 + colb;
            float bv = bias[col];
#pragma unroll
            for (int r = 0; r < 4; r++) {
                int grow = row0 + rb + r;
                float v = acc[t][r] + bv;
                if (RELU) v = fmaxf(v, 0.f);
                if (ZERO0 && grow == 0) v = 0.f;
                ((float*)outv)[(size_t)grow * DIM + col] = v;
            }
        }
    }
}

extern "C" void kernel_launch(void* const* d_in, const int* in_sizes, int n_in,
                              void* d_out, int out_size, void* d_ws, size_t ws_size,
                              hipStream_t stream) {
    const float* emb = (const float*)d_in[0];
    const float* w1  = (const float*)d_in[1];
    const float* b1  = (const float*)d_in[2];
    const float* w2  = (const float*)d_in[3];
    const float* b2  = (const float*)d_in[4];
    const float* eps = (const float*)d_in[5];
    const float* ew  = (const float*)d_in[6];
    const int* src   = (const int*)d_in[7];
    const int* dst   = (const int*)d_in[8];
    float* out = (float*)d_out;

    char* base = (char*)d_ws;
    size_t off = 0;
    auto alloc = [&](size_t bytes) -> char* {
        char* p = base + off;
        off += (bytes + 255) & ~(size_t)255;
        return p;
    };
    int* deg            = (int*)alloc((size_t)N_NODES * 4);
    int* row_start      = (int*)alloc((size_t)(N_NODES + 1) * 4);
    int* rank           = (int*)alloc((size_t)N_EDGES * 4);
    int* bsum           = (int*)alloc(128 * 4);
    int* bscan          = (int*)alloc(128 * 4);
    int2* sw_s          = (int2*)alloc((size_t)N_EDGES * 8);
    __hip_bfloat16* xb  = (__hip_bfloat16*)alloc((size_t)N_NODES * DIM * 2);
    __hip_bfloat16* xc  = (__hip_bfloat16*)alloc((size_t)N_NODES * DIM * 2);
    __hip_bfloat16* embb= (__hip_bfloat16*)alloc((size_t)N_NODES * DIM * 2);
    __hip_bfloat16* w1b = (__hip_bfloat16*)alloc(DIM * DIM * 2);
    __hip_bfloat16* w2b = (__hip_bfloat16*)alloc(DIM * DIM * 2);

    hipMemsetAsync(deg, 0, (size_t)N_NODES * 4, stream);

    // dtype conversions (one launch)
    {
        int n4 = N_NODES * DIM / 4 + 2 * (DIM * DIM / 4);
        cvtall_kernel<<<(n4 + 255) / 256, 256, 0, stream>>>(emb, w1, w2, embb, w1b, w2b);
    }

    // CSR build (atomic-free scatter via precomputed ranks)
    degrank_kernel<<<2048, 256, 0, stream>>>(dst, deg, rank);
    int nb = (N_NODES + SCAN_CHUNK - 1) / SCAN_CHUNK;
    scan1_kernel<<<nb, 256, 0, stream>>>(deg, bsum);
    scan2_kernel<<<1, 64, 0, stream>>>(bsum, bscan, row_start, nb);
    scan3_kernel<<<nb, 256, 0, stream>>>(deg, bscan, row_start);
    {
        int nthreads = ((N_EDGES + FI_UNROLL - 1) / FI_UNROLL + 255) & ~255;
        fill_kernel<<<nthreads / 256, 256, 0, stream>>>(src, dst, ew, rank, row_start, sw_s);
    }

    // fused layers (ping-pong buffers: embb -> xb -> xc -> out)
    int blocks = N_NODES / 16;  // 6250, exact
    aggmm_kernel<1, 0, 1><<<blocks, 256, 0, stream>>>(embb, row_start, sw_s, eps, 0, w1b, b1, xb);
    aggmm_kernel<1, 0, 1><<<blocks, 256, 0, stream>>>(xb,   row_start, sw_s, eps, 1, w2b, b2, xc);
    aggmm_kernel<0, 1, 0><<<blocks, 256, 0, stream>>>(xc,   row_start, sw_s, eps, 2, w2b, b2, out);
}

// Round 11
// 458.703 us; speedup vs baseline: 1.4283x; 1.0857x over previous
//
#include <hip/hip_runtime.h>
#include <hip/hip_bf16.h>

#define N_NODES 100000
#define N_EDGES 1600000
#define DIM 128
#define SCAN_CHUNK 1024

typedef __attribute__((ext_vector_type(8))) short bf16x8;
typedef __attribute__((ext_vector_type(4))) float f32x4;
typedef __attribute__((ext_vector_type(4))) short bf16x4;

__device__ __forceinline__ float b2f(short s) {
    return __uint_as_float(((unsigned int)(unsigned short)s) << 16);
}

// fp32 -> bf16 for emb + w1 + w2 in ONE launch (4 elems/thread)
__global__ void cvtall_kernel(const float* __restrict__ emb, const float* __restrict__ w1,
                              const float* __restrict__ w2, __hip_bfloat16* __restrict__ embb,
                              __hip_bfloat16* __restrict__ w1b, __hip_bfloat16* __restrict__ w2b) {
    const int n4e = N_NODES * DIM / 4;
    const int n4w = DIM * DIM / 4;
    int i = blockIdx.x * blockDim.x + threadIdx.x;
    const float* in;
    __hip_bfloat16* out;
    int j;
    if (i < n4e) { in = emb; out = embb; j = i; }
    else if (i < n4e + n4w) { in = w1; out = w1b; j = i - n4e; }
    else if (i < n4e + 2 * n4w) { in = w2; out = w2b; j = i - n4e - n4w; }
    else return;
    f32x4 v = ((const f32x4*)in)[j];
    bf16x4 o;
    o.x = (short)__bfloat16_as_ushort(__float2bfloat16(v.x));
    o.y = (short)__bfloat16_as_ushort(__float2bfloat16(v.y));
    o.z = (short)__bfloat16_as_ushort(__float2bfloat16(v.z));
    o.w = (short)__bfloat16_as_ushort(__float2bfloat16(v.w));
    ((bf16x4*)out)[j] = o;
}

// degree count + per-edge within-dst rank at FULL residency (2048x256 threads).
// 4 slots/thread: slots 0-2 always in-bounds (3S < N_EDGES), slot 3 covers the tail.
__global__ __launch_bounds__(256) void degrank_kernel(const int* __restrict__ dst,
                                                      int* __restrict__ deg,
                                                      int* __restrict__ rank) {
    const int S = 2048 * 256;
    int tid = blockIdx.x * blockDim.x + threadIdx.x;
    int e3 = tid + 3 * S;
    int d0 = dst[tid];
    int d1 = dst[tid + S];
    int d2 = dst[tid + 2 * S];
    int d3 = (e3 < N_EDGES) ? dst[e3] : -1;
    int r0 = atomicAdd(&deg[d0], 1);
    int r1 = atomicAdd(&deg[d1], 1);
    int r2 = atomicAdd(&deg[d2], 1);
    int r3 = (d3 >= 0) ? atomicAdd(&deg[d3], 1) : 0;
    rank[tid] = r0;
    rank[tid + S] = r1;
    rank[tid + 2 * S] = r2;
    if (e3 < N_EDGES) rank[e3] = r3;
}

// per-block partial sums over chunks of 1024
__global__ void scan1_kernel(const int* __restrict__ deg, int* __restrict__ bsum) {
    __shared__ int s[256];
    int t = threadIdx.x;
    int base = blockIdx.x * SCAN_CHUNK + t * 4;
    int v = 0;
    for (int k = 0; k < 4; k++) { int i = base + k; if (i < N_NODES) v += deg[i]; }
    s[t] = v;
    __syncthreads();
    for (int off = 128; off > 0; off >>= 1) { if (t < off) s[t] += s[t + off]; __syncthreads(); }
    if (t == 0) bsum[blockIdx.x] = s[0];
}

__global__ void scan2_kernel(const int* __restrict__ bsum, int* __restrict__ bscan,
                             int* __restrict__ row_start, int nb) {
    if (threadIdx.x == 0) {
        int run = 0;
        for (int b = 0; b < nb; b++) { bscan[b] = run; run += bsum[b]; }
        row_start[N_NODES] = run;
    }
}

__global__ void scan3_kernel(const int* __restrict__ deg, const int* __restrict__ bscan,
                             int* __restrict__ row_start) {
    __shared__ int s[256];
    int t = threadIdx.x;
    int base = blockIdx.x * SCAN_CHUNK + t * 4;
    int v[4]; int tot = 0;
    for (int k = 0; k < 4; k++) { int i = base + k; v[k] = (i < N_NODES) ? deg[i] : 0; tot += v[k]; }
    s[t] = tot;
    __syncthreads();
    for (int off = 1; off < 256; off <<= 1) {
        int a = (t >= off) ? s[t - off] : 0;
        __syncthreads();
        s[t] += a;
        __syncthreads();
    }
    int run = s[t] - tot + bscan[blockIdx.x];  // exclusive prefix for this thread
    for (int k = 0; k < 4; k++) {
        int i = base + k;
        if (i < N_NODES) row_start[i] = run;
        run += v[k];
    }
}

// atomic-free scatter, 4 edges per thread batched for ILP.
// Stores PRE-SCALED src row byte-offset (src*256) to save per-edge addr math in agg.
#define FI_UNROLL 4
__global__ void fill_kernel(const int* __restrict__ src, const int* __restrict__ dst,
                            const float* __restrict__ ew, const int* __restrict__ rank,
                            const int* __restrict__ row_start, int2* __restrict__ sw_s) {
    int tid = blockIdx.x * blockDim.x + threadIdx.x;
    int nthreads = gridDim.x * blockDim.x;
    int d_[FI_UNROLL], r_[FI_UNROLL], s_[FI_UNROLL], w_[FI_UNROLL], rs_[FI_UNROLL];
#pragma unroll
    for (int k = 0; k < FI_UNROLL; k++) {
        int e = tid + k * nthreads;
        if (e < N_EDGES) {
            d_[k] = dst[e]; r_[k] = rank[e]; s_[k] = src[e] << 8; w_[k] = __float_as_int(ew[e]);
        } else d_[k] = -1;
    }
#pragma unroll
    for (int k = 0; k < FI_UNROLL; k++)
        if (d_[k] >= 0) rs_[k] = row_start[d_[k]];
#pragma unroll
    for (int k = 0; k < FI_UNROLL; k++)
        if (d_[k] >= 0) sw_s[rs_[k] + r_[k]] = make_int2(s_[k], w_[k]);
}

// Fused aggregate + GEMM. Block = 4 waves owns a 16-row tile (N_NODES % 16 == 0).
// Agg: each wave owns 4 nodes, processed CONCURRENTLY (node-interleaved pipeline):
//   - masked global loads of all 4 first edge-chunks (zero-pad in dead lanes)
//   - 4 ds_writes, one lgkmcnt(0)
//   - joint gather loop over max cnt: 4 gathers/iter in flight (pads hit L1-hot row 0)
// Half-wave edge pairing: lane owns 4 channels (bf16x4); lanes 0-31 even edges,
// 32-63 odd edges; __shfl_xor(32) combines. deg>64 tail via serial fallback.
// GEMM: column-split across waves; bf16 out staged in LDS for coalesced stores.
template <int RELU, int ZERO0, int OUTBF>
__global__ __launch_bounds__(256) void aggmm_kernel(const __hip_bfloat16* __restrict__ x,
                                                    const int* __restrict__ row_start,
                                                    const int2* __restrict__ sw_s,
                                                    const float* __restrict__ eps, int li,
                                                    const __hip_bfloat16* __restrict__ W,
                                                    const float* __restrict__ bias,
                                                    void* __restrict__ outv) {
    __shared__ int2 s_sw[4][4][64];           // [wave][node][slot], 8 KB
    __shared__ __hip_bfloat162 s_h[16][64];   // 4 KB tile, XOR-swizzled
    int wv = threadIdx.x >> 6;
    int lane = threadIdx.x & 63;
    int row0 = blockIdx.x * 16;
    int c = lane & 31;        // channel group: channels [4c, 4c+4)
    int half = lane >> 5;     // 0: even edges, 1: odd edges
    const char* xb = (const char*)x + (c << 3);
    float ep = 1.0f + eps[li];

    int n0 = row0 + wv * 4;
    int beg[4], cnt[4];
#pragma unroll
    for (int j = 0; j < 4; j++) {
        beg[j] = row_start[n0 + j];
        cnt[j] = row_start[n0 + j + 1] - beg[j];
    }

    // issue self-row loads + all 4 first edge-chunk loads (masked, zero-pad) upfront
    bf16x4 xs[4];
#pragma unroll
    for (int j = 0; j < 4; j++)
        xs[j] = *(const bf16x4*)((const char*)x + (size_t)(n0 + j) * 256 + (c << 3));
    int2 er[4];
#pragma unroll
    for (int j = 0; j < 4; j++) {
        er[j] = make_int2(0, 0);
        if (lane < cnt[j]) er[j] = sw_s[beg[j] + lane];
    }
#pragma unroll
    for (int j = 0; j < 4; j++) s_sw[wv][j][lane] = er[j];
    asm volatile("s_waitcnt lgkmcnt(0)" ::: "memory");

    float acc[4][4] = {};
    int cmax = max(max(cnt[0], cnt[1]), max(cnt[2], cnt[3]));
    int c0 = min(cmax, 64);
    int c02 = (c0 + 1) & ~1;
    // joint gather loop: 4 nodes' chains interleaved (4 loads in flight per iter)
#pragma unroll 2
    for (int i = 0; i < c02; i += 2) {
#pragma unroll
        for (int j = 0; j < 4; j++) {
            int2 e = s_sw[wv][j][i + half];
            bf16x4 v = *(const bf16x4*)(xb + e.x);
            float w = __int_as_float(e.y);
            acc[j][0] += b2f(v.x) * w;
            acc[j][1] += b2f(v.y) * w;
            acc[j][2] += b2f(v.z) * w;
            acc[j][3] += b2f(v.w) * w;
        }
    }
    asm volatile("" ::: "memory");

    // rare fallback: nodes with deg > 64, serial per node
    if (cmax > 64) {
#pragma unroll 1
        for (int j = 0; j < 4; j++) {
            int nd = cnt[j];
#pragma unroll 1
            for (int base = 64; base < nd; base += 64) {
                int cc = min(64, nd - base);
                int2 er2 = make_int2(0, 0);
                if (lane < cc) er2 = sw_s[beg[j] + base + lane];
                s_sw[wv][j][lane] = er2;
                asm volatile("s_waitcnt lgkmcnt(0)" ::: "memory");
                int cc2 = (cc + 1) & ~1;
                for (int i = 0; i < cc2; i += 2) {
                    int2 e = s_sw[wv][j][i + half];
                    bf16x4 v = *(const bf16x4*)(xb + e.x);
                    float w = __int_as_float(e.y);
                    acc[j][0] += b2f(v.x) * w;
                    acc[j][1] += b2f(v.y) * w;
                    acc[j][2] += b2f(v.z) * w;
                    acc[j][3] += b2f(v.w) * w;
                }
                asm volatile("" ::: "memory");
            }
        }
    }

    // finalize: combine halves, self term, bf16 round, swizzled LDS tile write
#pragma unroll
    for (int j = 0; j < 4; j++) {
        float a0 = acc[j][0] + __shfl_xor(acc[j][0], 32, 64);
        float a1 = acc[j][1] + __shfl_xor(acc[j][1], 32, 64);
        float a2 = acc[j][2] + __shfl_xor(acc[j][2], 32, 64);
        float a3 = acc[j][3] + __shfl_xor(acc[j][3], 32, 64);
        if (half == 0) {
            float dinv = cnt[j] > 0 ? 1.0f / (float)cnt[j] : 0.0f;
            bf16x4 o;
            o.x = (short)__bfloat16_as_ushort(__float2bfloat16(ep * b2f(xs[j].x) + a0 * dinv));
            o.y = (short)__bfloat16_as_ushort(__float2bfloat16(ep * b2f(xs[j].y) + a1 * dinv));
            o.z = (short)__bfloat16_as_ushort(__float2bfloat16(ep * b2f(xs[j].z) + a2 * dinv));
            o.w = (short)__bfloat16_as_ushort(__float2bfloat16(ep * b2f(xs[j].w) + a3 * dinv));
            int jr = wv * 4 + j;
            int co = (c * 8) ^ ((jr & 7) << 4);
            *(bf16x4*)((char*)&s_h[jr][0] + co) = o;
        }
    }
    __syncthreads();  // tile produced by all 4 waves

    // ---- GEMM phase: each wave does cols [wv*32, wv*32+32) ----
    int lr = lane & 15;   // A/W row
    int kg = lane >> 4;   // k-subgroup (8 elements each)
    bf16x8 a[4];
#pragma unroll
    for (int k = 0; k < 4; k++) {
        int cb = (kg * 16 + k * 64) ^ ((lr & 7) << 4);
        a[k] = *(const bf16x8*)((const char*)&s_h[lr][0] + cb);
    }
    __syncthreads();  // a-frags in registers; s_h free for epilogue reuse

    f32x4 accm[2];
#pragma unroll
    for (int t = 0; t < 2; t++) {
        int jt = wv * 2 + t;
        const short* Wp = (const short*)W + (size_t)(jt * 16 + lr) * DIM + kg * 8;
        f32x4 cc = {0.f, 0.f, 0.f, 0.f};
#pragma unroll
        for (int k = 0; k < 4; k++) {
            bf16x8 b = *(const bf16x8*)(Wp + k * 32);
            cc = __builtin_amdgcn_mfma_f32_16x16x32_bf16(a[k], b, cc, 0, 0, 0);
        }
        accm[t] = cc;
    }

    int colb = lane & 15;
    int rb = (lane >> 4) * 4;
    if (OUTBF) {
        // stage out-tile in LDS (row-XOR swizzle), then 256 x 16B coalesced stores
#pragma unroll
        for (int t = 0; t < 2; t++) {
            int col = (wv * 2 + t) * 16 + colb;
            float bv = bias[col];
#pragma unroll
            for (int r = 0; r < 4; r++) {
                int row = rb + r;
                float v = accm[t][r] + bv;
                if (RELU) v = fmaxf(v, 0.f);
                if (ZERO0 && blockIdx.x == 0 && row == 0) v = 0.f;
                int bo = (row * 256 + col * 2) ^ ((row & 7) << 4);
                *(__hip_bfloat16*)((char*)s_h + bo) = __float2bfloat16(v);
            }
        }
        __syncthreads();
        int row = threadIdx.x >> 4, c16 = threadIdx.x & 15;
        int bo = (row * 256 + c16 * 16) ^ ((row & 7) << 4);
        bf16x8 vv = *(const bf16x8*)((const char*)s_h + bo);
        *(bf16x8*)((char*)outv + (size_t)(row0 + row) * 256 + c16 * 16) = vv;
    } else {
#pragma unroll
        for (int t = 0; t < 2; t++) {
            int col = (wv * 2 + t) * 16 + colb;
            float bv = bias[col];
#pragma unroll
            for (int r = 0; r < 4; r++) {
                int grow = row0 + rb + r;
                float v = accm[t][r] + bv;
                if (RELU) v = fmaxf(v, 0.f);
                if (ZERO0 && grow == 0) v = 0.f;
                ((float*)outv)[(size_t)grow * DIM + col] = v;
            }
        }
    }
}

extern "C" void kernel_launch(void* const* d_in, const int* in_sizes, int n_in,
                              void* d_out, int out_size, void* d_ws, size_t ws_size,
                              hipStream_t stream) {
    const float* emb = (const float*)d_in[0];
    const float* w1  = (const float*)d_in[1];
    const float* b1  = (const float*)d_in[2];
    const float* w2  = (const float*)d_in[3];
    const float* b2  = (const float*)d_in[4];
    const float* eps = (const float*)d_in[5];
    const float* ew  = (const float*)d_in[6];
    const int* src   = (const int*)d_in[7];
    const int* dst   = (const int*)d_in[8];
    float* out = (float*)d_out;

    char* base = (char*)d_ws;
    size_t off = 0;
    auto alloc = [&](size_t bytes) -> char* {
        char* p = base + off;
        off += (bytes + 255) & ~(size_t)255;
        return p;
    };
    int* deg            = (int*)alloc((size_t)N_NODES * 4);
    int* row_start      = (int*)alloc((size_t)(N_NODES + 1) * 4);
    int* rank           = (int*)alloc((size_t)N_EDGES * 4);
    int* bsum           = (int*)alloc(128 * 4);
    int* bscan          = (int*)alloc(128 * 4);
    int2* sw_s          = (int2*)alloc((size_t)N_EDGES * 8);
    __hip_bfloat16* xb  = (__hip_bfloat16*)alloc((size_t)N_NODES * DIM * 2);
    __hip_bfloat16* xc  = (__hip_bfloat16*)alloc((size_t)N_NODES * DIM * 2);
    __hip_bfloat16* embb= (__hip_bfloat16*)alloc((size_t)N_NODES * DIM * 2);
    __hip_bfloat16* w1b = (__hip_bfloat16*)alloc(DIM * DIM * 2);
    __hip_bfloat16* w2b = (__hip_bfloat16*)alloc(DIM * DIM * 2);

    hipMemsetAsync(deg, 0, (size_t)N_NODES * 4, stream);

    // dtype conversions (one launch)
    {
        int n4 = N_NODES * DIM / 4 + 2 * (DIM * DIM / 4);
        cvtall_kernel<<<(n4 + 255) / 256, 256, 0, stream>>>(emb, w1, w2, embb, w1b, w2b);
    }

    // CSR build (atomic-free scatter via precomputed ranks)
    degrank_kernel<<<2048, 256, 0, stream>>>(dst, deg, rank);
    int nb = (N_NODES + SCAN_CHUNK - 1) / SCAN_CHUNK;
    scan1_kernel<<<nb, 256, 0, stream>>>(deg, bsum);
    scan2_kernel<<<1, 64, 0, stream>>>(bsum, bscan, row_start, nb);
    scan3_kernel<<<nb, 256, 0, stream>>>(deg, bscan, row_start);
    {
        int nthreads = ((N_EDGES + FI_UNROLL - 1) / FI_UNROLL + 255) & ~255;
        fill_kernel<<<nthreads / 256, 256, 0, stream>>>(src, dst, ew, rank, row_start, sw_s);
    }

    // fused layers (ping-pong buffers: embb -> xb -> xc -> out)
    int blocks = N_NODES / 16;  // 6250, exact
    aggmm_kernel<1, 0, 1><<<blocks, 256, 0, stream>>>(embb, row_start, sw_s, eps, 0, w1b, b1, xb);
    aggmm_kernel<1, 0, 1><<<blocks, 256, 0, stream>>>(xb,   row_start, sw_s, eps, 1, w2b, b2, xc);
    aggmm_kernel<0, 1, 0><<<blocks, 256, 0, stream>>>(xc,   row_start, sw_s, eps, 2, w2b, b2, out);
}